// Round 4
// baseline (4432.550 us; speedup 1.0000x reference)
//
#include <hip/hip_runtime.h>
#include <hip/hip_bf16.h>
#include <stdint.h>

// MultilayerPCN: bf16-MFMA + split-K with in-kernel "last block finishes" reduction.
// NODES = [2048, 4096, 8192], B = 256, n_iters = 8 (hardcoded), LAMB = 0.5.
//
// R3 post-mortem: split-K GEMM phases were fast, but the separate pcn_epi
// reduction kernels ran at 277 GB/s effective (latency-bound partial round-trip
// + same-address atomic storms) and dominated. R4 keeps split-K occupancy and
// fuses reduction+epilogue back into the GEMM via flag-based tile finishers.
//
// Per iteration, 2 launches:
//   phase1: [G2 = e2@W1 (NS=4)  || G1 = e1@W0 (NS=4)]   768 blocks
//           finishers: EPI2 (v1 update,T1b) / EPI1 (v0 update,T0b,loss ne0)
//   phase2: [G4 = T1@W1^T (NS=2) || G3 = T0@W0^T (NS=4)] 1024 blocks
//           finishers: EPI4 (e2b,loss ne2) / EPI3 (e1/e1b,loss ne1)
//
// GEMM tile: BM=128, BN=64, BK=32; 256 thr (4 waves 2x2); global_load_lds
// width-16 staging; mfma_f32_16x16x32_bf16; fp32 partials in contiguous
// 32KB/slot; device-scope fences for cross-XCD visibility (guide G16).

typedef short short8x __attribute__((ext_vector_type(8)));
typedef float float4x __attribute__((ext_vector_type(4)));
typedef unsigned short u16;
typedef u16 u16x4 __attribute__((ext_vector_type(4)));

static constexpr float LOSS_SCALE = 100.0f / 256.0f;

__device__ __forceinline__ u16 f2b(float x) {
    union { float f; uint32_t u; } v{x};
    uint32_t b = v.u + 0x7fffu + ((v.u >> 16) & 1u);
    return (u16)(b >> 16);
}

__device__ __forceinline__ float signf_(float x) {
    return (x > 0.f) ? 1.f : ((x < 0.f) ? -1.f : 0.f);
}

__device__ __forceinline__ void gload_lds16(const void* g, void* lds) {
    __builtin_amdgcn_global_load_lds(
        (const __attribute__((address_space(1))) void*)g,
        (__attribute__((address_space(3))) void*)lds, 16, 0, 0);
}

// ---------------- init / cast kernels ----------------
__global__ void k_zero(float* p, int n) {
    int i = blockIdx.x * blockDim.x + threadIdx.x;
    if (i < n) p[i] = 0.f;
}

__global__ void k_cast(const float* __restrict__ in, u16* __restrict__ out, int n) {
    int i = blockIdx.x * blockDim.x + threadIdx.x;
    if (i < n) out[i] = f2b(in[i]);
}

__global__ __launch_bounds__(256) void k_transpose_cast(
    const float* __restrict__ in, u16* __restrict__ out, int R, int C) {
    __shared__ float tile[32][33];
    int x = blockIdx.x * 32 + threadIdx.x;
#pragma unroll
    for (int k = 0; k < 32; k += 8) {
        int y = blockIdx.y * 32 + threadIdx.y + k;
        tile[threadIdx.y + k][threadIdx.x] = in[(size_t)y * C + x];
    }
    __syncthreads();
    int ox = blockIdx.y * 32 + threadIdx.x;
#pragma unroll
    for (int k = 0; k < 32; k += 8) {
        int oy = blockIdx.x * 32 + threadIdx.y + k;
        out[(size_t)oy * R + ox] = f2b(tile[threadIdx.x][threadIdx.y + k]);
    }
}

__global__ void k_fill_v0(float* __restrict__ v0, const float* __restrict__ memory,
                          int n, int mask) {
    int i = blockIdx.x * blockDim.x + threadIdx.x;
    if (i < n) v0[i] = memory[i & mask];
}

__global__ void k_tanh(float* __restrict__ dst, const float* __restrict__ src, int n) {
    int i = blockIdx.x * blockDim.x + threadIdx.x;
    if (i < n) dst[i] = tanhf(src[i]);
}

__global__ void k_rowdot(const float* __restrict__ x, const float* __restrict__ W,
                         float* __restrict__ out, int K) {
    int i = blockIdx.x;
    const float* w = W + (size_t)i * K;
    float s = 0.f;
    for (int j = threadIdx.x; j < K; j += 256) s += x[j] * w[j];
    __shared__ float red[256];
    red[threadIdx.x] = s;
    __syncthreads();
    for (int st = 128; st > 0; st >>= 1) {
        if (threadIdx.x < st) red[threadIdx.x] += red[threadIdx.x + st];
        __syncthreads();
    }
    if (threadIdx.x == 0) out[i] = red[0];
}

__global__ void k_bcast_v1_e1(float* __restrict__ v1, float* __restrict__ e1,
                              u16* __restrict__ e1b,
                              const float* __restrict__ r1, int n, int mask) {
    int i = blockIdx.x * blockDim.x + threadIdx.x;
    if (i < n) { v1[i] = r1[i & mask]; e1[i] = 0.f; e1b[i] = 0; }
}

__global__ void k_e2_init(u16* __restrict__ e2b, const float* __restrict__ inp,
                          const float* __restrict__ r2, int n, int mask) {
    int i = blockIdx.x * blockDim.x + threadIdx.x;
    if (i < n) e2b[i] = f2b(inp[i] - r2[i & mask]);
}

// ---------------- split-K MFMA GEMM with fused finisher ----------------
struct GD {
    const u16* A;       // [256, K] bf16 row-major
    const u16* Bt;      // [N, K]  bf16 row-major (B transposed)
    float* Cp;          // partials: [tile][split][8192] fp32 (32KB slots)
    int* flags;         // one int per tile, zeroed at launch start
    const float* x0;    // epilogue input 0
    const float* x1;    // epilogue input 1
    float* y0;          // fp32 state output
    u16* y0b;           // bf16 copy of y0 (EPI3)
    u16* y1b;           // bf16 aux output (T0b/T1b/e2b)
    float* loss;        // loss accumulator (EPI != 2)
    const float* lr;    // inf_lr (EPI1/2)
    int N, K, nCol, Ksp, nBlocks;
};

template <int NS, int EPI>
__device__ void gemm_tile_sk(const GD& g, int bx, u16* As, u16* Bs) {
    const int tilesPer = 2 * g.nCol;
    const int split = bx / tilesPer;
    const int rc = bx - split * tilesPer;
    const int rowBlk = rc / g.nCol, colBlk = rc - rowBlk * g.nCol;

    const int t = threadIdx.x;
    const int w = t >> 6, l = t & 63;
    const int row0 = rowBlk * 128, col0 = colBlk * 64;
    const int K = g.K;
    const int kBeg = split * g.Ksp;

    // staging: per-thread 16B contiguous; A 8KB (2 issues), B 4KB (1 issue)
    const int srow = t >> 2;                 // 0..63
    const int scolE = (t & 3) << 3;          // 0/8/16/24 elements
    const u16* aptr0 = g.A + (size_t)(row0 + srow) * K + kBeg + scolE;
    const u16* aptr1 = g.A + (size_t)(row0 + 64 + srow) * K + kBeg + scolE;
    const u16* bptr  = g.Bt + (size_t)(col0 + srow) * K + kBeg + scolE;
    u16* alds0 = As + (w << 9);
    u16* alds1 = As + 2048 + (w << 9);
    u16* blds  = Bs + (w << 9);

    const int wm = (w >> 1) << 6;            // 0 / 64
    const int wn = (w & 1) << 5;             // 0 / 32
    const int lm = l & 15, lq = l >> 4;

    int aoff[4], boff[2];
#pragma unroll
    for (int i = 0; i < 4; ++i) aoff[i] = (wm + i * 16 + lm) * 32 + lq * 8;
#pragma unroll
    for (int j = 0; j < 2; ++j) boff[j] = (wn + j * 16 + lm) * 32 + lq * 8;

    float4x acc[4][2];
#pragma unroll
    for (int i = 0; i < 4; ++i)
#pragma unroll
        for (int j = 0; j < 2; ++j) acc[i][j] = (float4x)0.f;

    for (int k0 = 0; k0 < g.Ksp; k0 += 32) {
        gload_lds16(aptr0 + k0, alds0);
        gload_lds16(aptr1 + k0, alds1);
        gload_lds16(bptr + k0, blds);
        __syncthreads();
        short8x a[4], b[2];
#pragma unroll
        for (int i = 0; i < 4; ++i) a[i] = *(const short8x*)(As + aoff[i]);
#pragma unroll
        for (int j = 0; j < 2; ++j) b[j] = *(const short8x*)(Bs + boff[j]);
#pragma unroll
        for (int i = 0; i < 4; ++i)
#pragma unroll
            for (int j = 0; j < 2; ++j)
                acc[i][j] = __builtin_amdgcn_mfma_f32_16x16x32_bf16(a[i], b[j], acc[i][j], 0, 0, 0);
        __syncthreads();
    }

    // ---- store partial (contiguous 32KB slot; thread t owns floats [t*32, t*32+32)) ----
    float* slot = g.Cp + ((size_t)rc * NS + split) * 8192;
#pragma unroll
    for (int i = 0; i < 4; ++i)
#pragma unroll
        for (int j = 0; j < 2; ++j)
            *(float4x*)(slot + t * 32 + (i * 2 + j) * 4) = acc[i][j];

    // ---- release + flag; last block finishes ----
    __threadfence();
    __syncthreads();
    int* comm = (int*)As;   // As no longer needed
    if (t == 0) comm[0] = (atomicAdd(g.flags + rc, 1) == NS - 1) ? 1 : 0;
    __syncthreads();
    if (!comm[0]) return;
    __threadfence();        // acquire: see other splits' partials

    // ---- sum all NS slots ----
    const float* base = g.Cp + (size_t)rc * NS * 8192;
    float4x c[8];
#pragma unroll
    for (int q = 0; q < 8; ++q) c[q] = *(const float4x*)(base + t * 32 + q * 4);
#pragma unroll
    for (int s = 1; s < NS; ++s)
#pragma unroll
        for (int q = 0; q < 8; ++q)
            c[q] += *(const float4x*)(base + (size_t)s * 8192 + t * 32 + q * 4);

    // ---- fused epilogue (C/D layout: col = lane&15, row = (lane>>4)*4 + reg) ----
    float lr = 0.f;
    if (EPI == 1 || EPI == 2) lr = *g.lr;
    float lsum = 0.f;

#pragma unroll
    for (int i = 0; i < 4; ++i) {
#pragma unroll
        for (int j = 0; j < 2; ++j) {
#pragma unroll
            for (int r = 0; r < 4; ++r) {
                const int m = row0 + wm + i * 16 + lq * 4 + r;
                const int n = col0 + wn + j * 16 + lm;
                const size_t idx = (size_t)m * g.N + n;
                const float cv = c[i * 2 + j][r];
                if (EPI == 1) {
                    float v = g.x0[idx];            // v0
                    float mem = g.x1[n];            // memory
                    float th = tanhf(v), td = 1.f - th * th;
                    float d0 = (mem - v) - 0.5f * signf_(v) + td * cv;
                    float nv = v + lr * d0;
                    nv = nv > 0.f ? nv : 0.f;
                    g.y0[idx] = nv;                 // v0
                    g.y1b[idx] = f2b(tanhf(nv));    // T0b
                    float ne0 = nv - mem;
                    lsum += ne0 * ne0;
                } else if (EPI == 2) {
                    float v = g.x0[idx];            // v1
                    float e1v = g.x1[idx];          // e1 (pre-update)
                    float th = tanhf(v), td = 1.f - th * th;
                    float nv = v + lr * (-e1v + td * cv);
                    nv = nv > 0.f ? nv : 0.f;
                    g.y0[idx] = nv;                 // v1
                    g.y1b[idx] = f2b(tanhf(nv));    // T1b
                } else if (EPI == 3) {
                    float ne1 = g.x0[idx] - cv;     // v1 (updated) - pred1
                    g.y0[idx] = ne1;                // e1 f32
                    g.y0b[idx] = f2b(ne1);          // e1 bf16
                    lsum += ne1 * ne1;
                } else {
                    float ne2 = g.x0[idx] - cv;     // batch_inp - pred2
                    g.y1b[idx] = f2b(ne2);          // e2 bf16
                    lsum += ne2 * ne2;
                }
            }
        }
    }

    if (EPI != 2) {
#pragma unroll
        for (int off = 32; off > 0; off >>= 1) lsum += __shfl_down(lsum, off);
        if (l == 0) atomicAdd(g.loss, lsum * LOSS_SCALE);
    }
}

template <int NSA, int EPIA, int NSB, int EPIB>
__global__ __launch_bounds__(256) void pcn_pair(GD ga, GD gb, int nA) {
    __shared__ u16 As[4096];   // 8 KB
    __shared__ u16 Bs[2048];   // 4 KB
    int bx = blockIdx.x;
    if (bx < nA) gemm_tile_sk<NSA, EPIA>(ga, bx, As, Bs);
    else         gemm_tile_sk<NSB, EPIB>(gb, bx - nA, As, Bs);
}

extern "C" void kernel_launch(void* const* d_in, const int* in_sizes, int n_in,
                              void* d_out, int out_size, void* d_ws, size_t ws_size,
                              hipStream_t stream)
{
    const float* batch_inp = (const float*)d_in[0]; // (256, 8192)
    const float* W0        = (const float*)d_in[1]; // (4096, 2048)
    const float* W1        = (const float*)d_in[2]; // (8192, 4096)
    const float* memory    = (const float*)d_in[3]; // (2048,)
    const float* lr_ptr    = (const float*)d_in[5]; // 0.05
    float* out = (float*)d_out;                     // 8 losses

    const int n0 = 2048, n1 = 4096, n2 = 8192, Bn = 256;

    // ---- workspace layout ----
    char* ws = (char*)d_ws;
    auto alloc_f = [&](size_t n) { float* p = (float*)ws; ws += n * 4; return p; };
    auto alloc_b = [&](size_t n) { u16* p = (u16*)ws; ws += n * 2; return p; };

    float* v0  = alloc_f((size_t)Bn * n0);
    float* v1  = alloc_f((size_t)Bn * n1);
    float* e1  = alloc_f((size_t)Bn * n1);
    u16*   e1b = alloc_b((size_t)Bn * n1);
    u16*   e2b = alloc_b((size_t)Bn * n2);
    u16*   T0b = alloc_b((size_t)Bn * n0);
    u16*   T1b = alloc_b((size_t)Bn * n1);
    u16*   W0b  = alloc_b((size_t)n1 * n0);
    u16*   W0Tb = alloc_b((size_t)n0 * n1);
    u16*   W1b  = alloc_b((size_t)n2 * n1);
    u16*   W1Tb = alloc_b((size_t)n1 * n2);
    float* CpA = alloc_f((size_t)128 * 4 * 8192);   // 16 MB: G2(128t x NS4) / G4(256t x NS2)
    float* CpB = alloc_f((size_t)128 * 4 * 8192);   // 16 MB: G1(64t x NS4) / G3(128t x NS4)
    int*   flags = (int*)alloc_f(8 * 576);          // per-iter: G1 64 | G2 128 | G3 128 | G4 256
    float* tm = alloc_f(n0);
    float* r1 = alloc_f(n1);
    float* t1 = alloc_f(n1);
    float* r2 = alloc_f(n2);

    // ---- one-time init ----
    k_zero<<<1, 32, 0, stream>>>(out, 8);
    k_zero<<<(8 * 576 + 255) / 256, 256, 0, stream>>>((float*)flags, 8 * 576);
    k_cast<<<(n1 * n0) / 256, 256, 0, stream>>>(W0, W0b, n1 * n0);
    k_cast<<<(n2 * n1) / 256, 256, 0, stream>>>(W1, W1b, n2 * n1);
    k_transpose_cast<<<dim3(n0 / 32, n1 / 32), dim3(32, 8), 0, stream>>>(W0, W0Tb, n1, n0);
    k_transpose_cast<<<dim3(n1 / 32, n2 / 32), dim3(32, 8), 0, stream>>>(W1, W1Tb, n2, n1);
    k_fill_v0<<<(Bn * n0) / 256, 256, 0, stream>>>(v0, memory, Bn * n0, n0 - 1);
    k_tanh<<<n0 / 256, 256, 0, stream>>>(tm, memory, n0);
    k_rowdot<<<n1, 256, 0, stream>>>(tm, W0, r1, n0);
    k_tanh<<<n1 / 256, 256, 0, stream>>>(t1, r1, n1);
    k_bcast_v1_e1<<<(Bn * n1) / 256, 256, 0, stream>>>(v1, e1, e1b, r1, Bn * n1, n1 - 1);
    k_rowdot<<<n2, 256, 0, stream>>>(t1, W1, r2, n1);
    k_e2_init<<<(Bn * n2) / 256, 256, 0, stream>>>(e2b, batch_inp, r2, Bn * n2, n2 - 1);

    // ---- 8 inference iterations ----
    for (int it = 0; it < 8; ++it) {
        float* loss = out + it;
        int* fl = flags + it * 576;

        // phase 1: G2 (K=8192, NS=4, 512 blk) || G1 (K=4096, NS=4, 256 blk)
        GD g2{e2b, W1Tb, CpA, fl + 64, v1, e1, v1, nullptr, T1b, nullptr, lr_ptr,
              n1, n2, n1 / 64, n2 / 4, 4 * 2 * (n1 / 64)};
        GD g1{e1b, W0Tb, CpB, fl + 0, v0, memory, v0, nullptr, T0b, loss, lr_ptr,
              n0, n1, n0 / 64, n1 / 4, 4 * 2 * (n0 / 64)};
        pcn_pair<4, 2, 4, 1><<<g2.nBlocks + g1.nBlocks, 256, 0, stream>>>(g2, g1, g2.nBlocks);

        // phase 2: G4 (K=4096, NS=2, 512 blk) || G3 (K=2048, NS=4, 512 blk)
        GD g4{T1b, W1b, CpA, fl + 320, batch_inp, nullptr, nullptr, nullptr, e2b, loss, nullptr,
              n2, n1, n2 / 64, n1 / 2, 2 * 2 * (n2 / 64)};
        GD g3{T0b, W0b, CpB, fl + 192, v1, nullptr, e1, e1b, nullptr, loss, nullptr,
              n1, n0, n1 / 64, n0 / 4, 4 * 2 * (n1 / 64)};
        pcn_pair<2, 4, 4, 3><<<g4.nBlocks + g3.nBlocks, 256, 0, stream>>>(g4, g3, g4.nBlocks);
    }
}

// Round 5
// 3129.642 us; speedup vs baseline: 1.4163x; 1.4163x over previous
//
#include <hip/hip_runtime.h>
#include <hip/hip_bf16.h>
#include <stdint.h>

// MultilayerPCN: bf16-MFMA, register-direct GEMM (no LDS, no barriers).
// NODES = [2048, 4096, 8192], B = 256, n_iters = 8 (hardcoded), LAMB = 0.5.
//
// R3/R4 post-mortem: global split-K reduction loses (partial round-trip thrashes
// L2 -> HBM; finisher tail serializes). R2's fused structure was right but
// latency-bound (3 waves/CU, barrier-drained K-loop). R5: since B^T is N x K
// row-major, each lane's MFMA fragment is 8 contiguous bf16 (16 B) -> load
// fragments straight global->VGPR. No LDS, no __syncthreads: waves free-run
// with depth-2 register pipelining; BM=BN=64 tiles give 384/768-block phases
// (~5 blocks/CU, 20 waves/CU) so cross-wave TLP hides L2/L3 latency.
//
// Per iteration, 2 merged launches:
//   phase1: [G2 = e2@W1 || G1 = e1@W0]     384 blocks
//   phase2: [G4 = T1@W1^T || G3 = T0@W0^T] 768 blocks
// Epilogues fused in-kernel (node update / tanh / errors / loss atomics).

typedef short short8x __attribute__((ext_vector_type(8)));
typedef float float4x __attribute__((ext_vector_type(4)));
typedef unsigned short u16;
typedef u16 u16x8 __attribute__((ext_vector_type(8)));

static constexpr float LOSS_SCALE = 100.0f / 256.0f;

__device__ __forceinline__ u16 f2b(float x) {
    union { float f; uint32_t u; } v{x};
    uint32_t b = v.u + 0x7fffu + ((v.u >> 16) & 1u);
    return (u16)(b >> 16);
}

__device__ __forceinline__ float signf_(float x) {
    return (x > 0.f) ? 1.f : ((x < 0.f) ? -1.f : 0.f);
}

// ---------------- init / cast kernels ----------------
__global__ void k_zero(float* p, int n) {
    int i = blockIdx.x * blockDim.x + threadIdx.x;
    if (i < n) p[i] = 0.f;
}

__global__ void k_cast8(const float* __restrict__ in, u16* __restrict__ out, int n) {
    int i = (blockIdx.x * 256 + threadIdx.x) * 8;
    if (i >= n) return;
    float4x a = *(const float4x*)(in + i);
    float4x b = *(const float4x*)(in + i + 4);
    u16x8 r;
#pragma unroll
    for (int q = 0; q < 4; ++q) { r[q] = f2b(a[q]); r[q + 4] = f2b(b[q]); }
    *(u16x8*)(out + i) = r;
}

// out (C x R bf16) = transpose(in (R x C f32))
__global__ __launch_bounds__(256) void k_transpose_cast(
    const float* __restrict__ in, u16* __restrict__ out, int R, int C) {
    __shared__ float tile[32][33];
    int x = blockIdx.x * 32 + threadIdx.x;
#pragma unroll
    for (int k = 0; k < 32; k += 8) {
        int y = blockIdx.y * 32 + threadIdx.y + k;
        tile[threadIdx.y + k][threadIdx.x] = in[(size_t)y * C + x];
    }
    __syncthreads();
    int ox = blockIdx.y * 32 + threadIdx.x;
#pragma unroll
    for (int k = 0; k < 32; k += 8) {
        int oy = blockIdx.x * 32 + threadIdx.y + k;
        out[(size_t)oy * R + ox] = f2b(tile[threadIdx.x][threadIdx.y + k]);
    }
}

__global__ void k_fill_v0(float* __restrict__ v0, const float* __restrict__ memory,
                          int n, int mask) {
    int i = blockIdx.x * blockDim.x + threadIdx.x;
    if (i < n) v0[i] = memory[i & mask];
}

__global__ void k_tanh(float* __restrict__ dst, const float* __restrict__ src, int n) {
    int i = blockIdx.x * blockDim.x + threadIdx.x;
    if (i < n) dst[i] = tanhf(src[i]);
}

__global__ void k_rowdot(const float* __restrict__ x, const float* __restrict__ W,
                         float* __restrict__ out, int K) {
    int i = blockIdx.x;
    const float* w = W + (size_t)i * K;
    float s = 0.f;
    for (int j = threadIdx.x; j < K; j += 256) s += x[j] * w[j];
    __shared__ float red[256];
    red[threadIdx.x] = s;
    __syncthreads();
    for (int st = 128; st > 0; st >>= 1) {
        if (threadIdx.x < st) red[threadIdx.x] += red[threadIdx.x + st];
        __syncthreads();
    }
    if (threadIdx.x == 0) out[i] = red[0];
}

__global__ void k_bcast_v1_e1(float* __restrict__ v1, float* __restrict__ e1,
                              u16* __restrict__ e1b,
                              const float* __restrict__ r1, int n, int mask) {
    int i = blockIdx.x * blockDim.x + threadIdx.x;
    if (i < n) { v1[i] = r1[i & mask]; e1[i] = 0.f; e1b[i] = 0; }
}

__global__ void k_e2_init(u16* __restrict__ e2b, const float* __restrict__ inp,
                          const float* __restrict__ r2, int n, int mask) {
    int i = blockIdx.x * blockDim.x + threadIdx.x;
    if (i < n) e2b[i] = f2b(inp[i] - r2[i & mask]);
}

// ---------------- register-direct MFMA GEMM ----------------
struct GDR {
    const u16* A;       // [256, K] bf16 row-major
    const u16* Bt;      // [N, K]  bf16 row-major (B transposed)
    const float* x0;    // epilogue input 0
    const float* x1;    // epilogue input 1
    float* y0;          // fp32 state output
    u16* y0b;           // bf16 copy of y0 (EPI3)
    u16* y1b;           // bf16 aux output (T0b/T1b/e2b)
    float* loss;        // loss accumulator (EPI != 2)
    const float* lr;    // inf_lr (EPI1/2)
    int N, K, nCol;     // nCol = N/64; tiles = 4 * nCol
};

// 64x64 tile, 256 threads = 4 waves in 2x2 (each wave 32x32 = 2x2 mfma frags).
// Fragments loaded straight from global (16 B/lane); depth-2 pipeline; no LDS.
template <int EPI>
__device__ void gemm64(const GDR& g, int tile) {
    const int rowBlk = tile / g.nCol;
    const int colBlk = tile - rowBlk * g.nCol;
    const int t = threadIdx.x;
    const int w = t >> 6, l = t & 63;
    const int row0 = rowBlk * 64, col0 = colBlk * 64;
    const int wm = (w >> 1) << 5;            // 0 / 32
    const int wn = (w & 1) << 5;             // 0 / 32
    const int lm = l & 15, lq = l >> 4;
    const int K = g.K;

    // A fragment rows: row0+wm+i*16+lm; lane's k-slice: lq*8 .. lq*8+7 (16 B)
    const u16* ap0 = g.A + (size_t)(row0 + wm + lm) * K + lq * 8;
    const u16* ap1 = ap0 + (size_t)16 * K;
    const u16* bp0 = g.Bt + (size_t)(col0 + wn + lm) * K + lq * 8;
    const u16* bp1 = bp0 + (size_t)16 * K;

    float4x acc[2][2];
#pragma unroll
    for (int i = 0; i < 2; ++i)
#pragma unroll
        for (int j = 0; j < 2; ++j) acc[i][j] = (float4x)0.f;

    short8x a0[2], b0[2], a1[2], b1[2];

#define LD0(k) { a0[0] = *(const short8x*)(ap0 + (k)); a0[1] = *(const short8x*)(ap1 + (k)); \
                 b0[0] = *(const short8x*)(bp0 + (k)); b0[1] = *(const short8x*)(bp1 + (k)); }
#define LD1(k) { a1[0] = *(const short8x*)(ap0 + (k)); a1[1] = *(const short8x*)(ap1 + (k)); \
                 b1[0] = *(const short8x*)(bp0 + (k)); b1[1] = *(const short8x*)(bp1 + (k)); }
#define MM0()  { acc[0][0] = __builtin_amdgcn_mfma_f32_16x16x32_bf16(a0[0], b0[0], acc[0][0], 0, 0, 0); \
                 acc[0][1] = __builtin_amdgcn_mfma_f32_16x16x32_bf16(a0[0], b0[1], acc[0][1], 0, 0, 0); \
                 acc[1][0] = __builtin_amdgcn_mfma_f32_16x16x32_bf16(a0[1], b0[0], acc[1][0], 0, 0, 0); \
                 acc[1][1] = __builtin_amdgcn_mfma_f32_16x16x32_bf16(a0[1], b0[1], acc[1][1], 0, 0, 0); }
#define MM1()  { acc[0][0] = __builtin_amdgcn_mfma_f32_16x16x32_bf16(a1[0], b1[0], acc[0][0], 0, 0, 0); \
                 acc[0][1] = __builtin_amdgcn_mfma_f32_16x16x32_bf16(a1[0], b1[1], acc[0][1], 0, 0, 0); \
                 acc[1][0] = __builtin_amdgcn_mfma_f32_16x16x32_bf16(a1[1], b1[0], acc[1][0], 0, 0, 0); \
                 acc[1][1] = __builtin_amdgcn_mfma_f32_16x16x32_bf16(a1[1], b1[1], acc[1][1], 0, 0, 0); }

    // K is a multiple of 64 (2048/4096/8192)
    LD0(0);
    int k0 = 0;
    for (; k0 + 64 < K; k0 += 64) {
        LD1(k0 + 32);
        MM0();
        LD0(k0 + 64);
        MM1();
    }
    LD1(k0 + 32);
    MM0();
    MM1();
#undef LD0
#undef LD1
#undef MM0
#undef MM1

    // ---- fused epilogue (C/D layout: col = lane&15, row = (lane>>4)*4 + reg) ----
    float lr = 0.f;
    if (EPI == 1 || EPI == 2) lr = *g.lr;
    float lsum = 0.f;

#pragma unroll
    for (int i = 0; i < 2; ++i) {
#pragma unroll
        for (int j = 0; j < 2; ++j) {
#pragma unroll
            for (int r = 0; r < 4; ++r) {
                const int m = row0 + wm + i * 16 + lq * 4 + r;
                const int n = col0 + wn + j * 16 + lm;
                const size_t idx = (size_t)m * g.N + n;
                const float cv = acc[i][j][r];
                if (EPI == 1) {
                    float v = g.x0[idx];            // v0
                    float mem = g.x1[n];            // memory
                    float th = tanhf(v), td = 1.f - th * th;
                    float d0 = (mem - v) - 0.5f * signf_(v) + td * cv;
                    float nv = v + lr * d0;
                    nv = nv > 0.f ? nv : 0.f;
                    g.y0[idx] = nv;                 // v0
                    g.y1b[idx] = f2b(tanhf(nv));    // T0b
                    float ne0 = nv - mem;
                    lsum += ne0 * ne0;
                } else if (EPI == 2) {
                    float v = g.x0[idx];            // v1
                    float e1v = g.x1[idx];          // e1 (pre-update)
                    float th = tanhf(v), td = 1.f - th * th;
                    float nv = v + lr * (-e1v + td * cv);
                    nv = nv > 0.f ? nv : 0.f;
                    g.y0[idx] = nv;                 // v1
                    g.y1b[idx] = f2b(tanhf(nv));    // T1b
                } else if (EPI == 3) {
                    float ne1 = g.x0[idx] - cv;     // v1 (updated) - pred1
                    g.y0[idx] = ne1;                // e1 f32
                    g.y0b[idx] = f2b(ne1);          // e1 bf16
                    lsum += ne1 * ne1;
                } else {
                    float ne2 = g.x0[idx] - cv;     // batch_inp - pred2
                    g.y1b[idx] = f2b(ne2);          // e2 bf16
                    lsum += ne2 * ne2;
                }
            }
        }
    }

    if (EPI != 2) {
#pragma unroll
        for (int off = 32; off > 0; off >>= 1) lsum += __shfl_down(lsum, off);
        if (l == 0) atomicAdd(g.loss, lsum * LOSS_SCALE);
    }
}

template <int EPIA, int EPIB>
__global__ __launch_bounds__(256, 4) void pcn_gemm64(GDR ga, GDR gb, int nA) {
    int bx = blockIdx.x;
    if (bx < nA) gemm64<EPIA>(ga, bx);
    else         gemm64<EPIB>(gb, bx - nA);
}

extern "C" void kernel_launch(void* const* d_in, const int* in_sizes, int n_in,
                              void* d_out, int out_size, void* d_ws, size_t ws_size,
                              hipStream_t stream)
{
    const float* batch_inp = (const float*)d_in[0]; // (256, 8192)
    const float* W0        = (const float*)d_in[1]; // (4096, 2048)
    const float* W1        = (const float*)d_in[2]; // (8192, 4096)
    const float* memory    = (const float*)d_in[3]; // (2048,)
    const float* lr_ptr    = (const float*)d_in[5]; // 0.05
    float* out = (float*)d_out;                     // 8 losses

    const int n0 = 2048, n1 = 4096, n2 = 8192, Bn = 256;

    // ---- workspace layout ----
    char* ws = (char*)d_ws;
    auto alloc_f = [&](size_t n) { float* p = (float*)ws; ws += n * 4; return p; };
    auto alloc_b = [&](size_t n) { u16* p = (u16*)ws; ws += n * 2; return p; };

    float* v0  = alloc_f((size_t)Bn * n0);
    float* v1  = alloc_f((size_t)Bn * n1);
    float* e1  = alloc_f((size_t)Bn * n1);
    u16*   e1b = alloc_b((size_t)Bn * n1);
    u16*   e2b = alloc_b((size_t)Bn * n2);
    u16*   T0b = alloc_b((size_t)Bn * n0);
    u16*   T1b = alloc_b((size_t)Bn * n1);
    u16*   W0b  = alloc_b((size_t)n1 * n0);   // (n1, n0) = W0 cast
    u16*   W0Tb = alloc_b((size_t)n0 * n1);   // (n0, n1) = W0^T cast
    u16*   W1b  = alloc_b((size_t)n2 * n1);   // (n2, n1) = W1 cast
    u16*   W1Tb = alloc_b((size_t)n1 * n2);   // (n1, n2) = W1^T cast
    float* tm = alloc_f(n0);
    float* r1 = alloc_f(n1);
    float* t1 = alloc_f(n1);
    float* r2 = alloc_f(n2);

    // ---- one-time init ----
    k_zero<<<1, 32, 0, stream>>>(out, 8);
    k_cast8<<<(n1 * n0) / 2048, 256, 0, stream>>>(W0, W0b, n1 * n0);
    k_cast8<<<(n2 * n1) / 2048, 256, 0, stream>>>(W1, W1b, n2 * n1);
    k_transpose_cast<<<dim3(n0 / 32, n1 / 32), dim3(32, 8), 0, stream>>>(W0, W0Tb, n1, n0);
    k_transpose_cast<<<dim3(n1 / 32, n2 / 32), dim3(32, 8), 0, stream>>>(W1, W1Tb, n2, n1);
    k_fill_v0<<<(Bn * n0) / 256, 256, 0, stream>>>(v0, memory, Bn * n0, n0 - 1);
    k_tanh<<<n0 / 256, 256, 0, stream>>>(tm, memory, n0);
    k_rowdot<<<n1, 256, 0, stream>>>(tm, W0, r1, n0);        // r1 = tanh(mem) @ W0^T
    k_tanh<<<n1 / 256, 256, 0, stream>>>(t1, r1, n1);
    k_bcast_v1_e1<<<(Bn * n1) / 256, 256, 0, stream>>>(v1, e1, e1b, r1, Bn * n1, n1 - 1);
    k_rowdot<<<n2, 256, 0, stream>>>(t1, W1, r2, n1);        // r2 = tanh(r1) @ W1^T
    k_e2_init<<<(Bn * n2) / 256, 256, 0, stream>>>(e2b, batch_inp, r2, Bn * n2, n2 - 1);

    // ---- 8 inference iterations ----
    for (int it = 0; it < 8; ++it) {
        float* loss = out + it;

        // phase 1: G2 (256 tiles) || G1 (128 tiles) — 384 blocks
        GDR g2{e2b, W1Tb, v1, e1, v1, nullptr, T1b, nullptr, lr_ptr, n1, n2, n1 / 64};
        GDR g1{e1b, W0Tb, v0, memory, v0, nullptr, T0b, loss, lr_ptr, n0, n1, n0 / 64};
        pcn_gemm64<2, 1><<<4 * (n1 / 64) + 4 * (n0 / 64), 256, 0, stream>>>(
            g2, g1, 4 * (n1 / 64));

        // phase 2: G4 (512 tiles) || G3 (256 tiles) — 768 blocks
        GDR g4{T1b, W1b, batch_inp, nullptr, nullptr, nullptr, e2b, loss, nullptr, n2, n1, n2 / 64};
        GDR g3{T0b, W0b, v1, nullptr, e1, e1b, nullptr, loss, nullptr, n1, n0, n1 / 64};
        pcn_gemm64<4, 3><<<4 * (n2 / 64) + 4 * (n1 / 64), 256, 0, stream>>>(
            g4, g3, 4 * (n2 / 64));
    }
}

// Round 6
// 1424.244 us; speedup vs baseline: 3.1122x; 2.1974x over previous
//
#include <hip/hip_runtime.h>
#include <hip/hip_bf16.h>
#include <stdint.h>

// MultilayerPCN: bf16-MFMA, in-block 8-way K-split, barrier-free K-loop.
// NODES = [2048, 4096, 8192], B = 256, n_iters = 8 (hardcoded), LAMB = 0.5.
//
// Block = 512 thr = 8 waves; each wave computes the FULL 64x64 C-tile from its
// private K/8 slice (4x4 mfma_f32_16x16x32_bf16 frags, 64 fp32 acc). Staging:
// per-wave private double-buffered LDS (2 x 8KB per wave, 128KB/block) via
// global_load_lds width-16. No __syncthreads in the K-loop: per-wave
// s_waitcnt vmcnt(8) (prefetch depth 1, never drains to 0) with
// sched_barrier(0) fences. Partials tree-reduced in LDS (reusing staging),
// then fused 512-thread epilogue (node update / tanh / errors / loss).
//
// Per iteration, 2 launches:
//   phase1: [G2 = e2@W1 || G1 = e1@W0]     384 blocks
//   phase2: [G4 = T1@W1^T || G3 = T0@W0^T] 768 blocks

typedef short short8x __attribute__((ext_vector_type(8)));
typedef float float4x __attribute__((ext_vector_type(4)));
typedef unsigned short u16;
typedef u16 u16x8 __attribute__((ext_vector_type(8)));

static constexpr float LOSS_SCALE = 100.0f / 256.0f;

__device__ __forceinline__ u16 f2b(float x) {
    union { float f; uint32_t u; } v{x};
    uint32_t b = v.u + 0x7fffu + ((v.u >> 16) & 1u);
    return (u16)(b >> 16);
}

__device__ __forceinline__ float signf_(float x) {
    return (x > 0.f) ? 1.f : ((x < 0.f) ? -1.f : 0.f);
}

__device__ __forceinline__ void gload_lds16(const void* g, void* lds) {
    __builtin_amdgcn_global_load_lds(
        (const __attribute__((address_space(1))) void*)g,
        (__attribute__((address_space(3))) void*)lds, 16, 0, 0);
}

// ---------------- init / cast kernels ----------------
__global__ void k_zero(float* p, int n) {
    int i = blockIdx.x * blockDim.x + threadIdx.x;
    if (i < n) p[i] = 0.f;
}

// one pass: outN = bf16(in) (R x C), outT = bf16(in^T) (C x R)
__global__ __launch_bounds__(256) void k_cast_both(
    const float* __restrict__ in, u16* __restrict__ outN, u16* __restrict__ outT,
    int R, int C) {
    __shared__ float tile[32][33];
    int x = blockIdx.x * 32 + threadIdx.x;
#pragma unroll
    for (int k = 0; k < 32; k += 8) {
        int y = blockIdx.y * 32 + threadIdx.y + k;
        float v = in[(size_t)y * C + x];
        tile[threadIdx.y + k][threadIdx.x] = v;
        outN[(size_t)y * C + x] = f2b(v);
    }
    __syncthreads();
    int ox = blockIdx.y * 32 + threadIdx.x;
#pragma unroll
    for (int k = 0; k < 32; k += 8) {
        int oy = blockIdx.x * 32 + threadIdx.y + k;
        outT[(size_t)oy * R + ox] = f2b(tile[threadIdx.x][threadIdx.y + k]);
    }
}

__global__ void k_fill_v0(float* __restrict__ v0, const float* __restrict__ memory,
                          int n, int mask) {
    int i = blockIdx.x * blockDim.x + threadIdx.x;
    if (i < n) v0[i] = memory[i & mask];
}

__global__ void k_tanh(float* __restrict__ dst, const float* __restrict__ src, int n) {
    int i = blockIdx.x * blockDim.x + threadIdx.x;
    if (i < n) dst[i] = tanhf(src[i]);
}

__global__ void k_rowdot(const float* __restrict__ x, const float* __restrict__ W,
                         float* __restrict__ out, int K) {
    int i = blockIdx.x;
    const float* w = W + (size_t)i * K;
    float s = 0.f;
    for (int j = threadIdx.x; j < K; j += 256) s += x[j] * w[j];
    __shared__ float red[256];
    red[threadIdx.x] = s;
    __syncthreads();
    for (int st = 128; st > 0; st >>= 1) {
        if (threadIdx.x < st) red[threadIdx.x] += red[threadIdx.x + st];
        __syncthreads();
    }
    if (threadIdx.x == 0) out[i] = red[0];
}

__global__ void k_bcast_v1_e1(float* __restrict__ v1, float* __restrict__ e1,
                              u16* __restrict__ e1b,
                              const float* __restrict__ r1, int n, int mask) {
    int i = blockIdx.x * blockDim.x + threadIdx.x;
    if (i < n) { v1[i] = r1[i & mask]; e1[i] = 0.f; e1b[i] = 0; }
}

__global__ void k_e2_init(u16* __restrict__ e2b, const float* __restrict__ inp,
                          const float* __restrict__ r2, int n, int mask) {
    int i = blockIdx.x * blockDim.x + threadIdx.x;
    if (i < n) e2b[i] = f2b(inp[i] - r2[i & mask]);
}

// ---------------- in-block K-split MFMA GEMM ----------------
struct GDR {
    const u16* A;       // [256, K] bf16 row-major
    const u16* Bt;      // [N, K]  bf16 row-major (B transposed)
    const float* x0;    // epilogue input 0
    const float* x1;    // epilogue input 1
    float* y0;          // fp32 state output
    u16* y0b;           // bf16 copy of y0 (EPI3)
    u16* y1b;           // bf16 aux output (T0b/T1b/e2b)
    float* loss;        // loss accumulator (EPI != 2)
    const float* lr;    // inf_lr (EPI1/2)
    int N, K, nCol;     // nCol = N/64; tiles = 4*nCol
};

template <int EPI>
__device__ void gemm_tile(const GDR& g, int tile, u16* stage, float* red8) {
    const int t = threadIdx.x;
    const int w = t >> 6, l = t & 63;
    const int lm = l & 15, lq = l >> 4;
    const int rowBlk = tile / g.nCol, colBlk = tile - rowBlk * g.nCol;
    const int row0 = rowBlk * 64, col0 = colBlk * 64;
    const int K = g.K;
    const int Ksl = K >> 3;          // this wave's K-slice length
    const int nCh = Ksl >> 5;        // chunks of 32 (min 8)

    // per-wave private staging: 16KB region; buf b: A at b*4096 u16, B at +2048
    u16* base = stage + (w << 13);
    const u16* aSrc = g.A + (size_t)(row0 + (l >> 2)) * K + w * Ksl + (l & 3) * 8;
    const u16* bSrc = g.Bt + (size_t)(col0 + (l >> 2)) * K + w * Ksl + (l & 3) * 8;
    const size_t rStep = (size_t)16 * K;   // 16 rows per staging issue

    int aoff[4], boff[4];
#pragma unroll
    for (int i = 0; i < 4; ++i) { aoff[i] = (i * 16 + lm) * 32 + lq * 8; boff[i] = aoff[i]; }

    float4x acc[4][4];
#pragma unroll
    for (int i = 0; i < 4; ++i)
#pragma unroll
        for (int j = 0; j < 4; ++j) acc[i][j] = (float4x)0.f;

#define ISSUE(c, b) { \
    u16* ab = base + (b) * 4096; \
    const u16* as = aSrc + (c) * 32; \
    const u16* bs = bSrc + (c) * 32; \
    gload_lds16(as, ab);             gload_lds16(as + rStep, ab + 512); \
    gload_lds16(as + 2*rStep, ab + 1024); gload_lds16(as + 3*rStep, ab + 1536); \
    gload_lds16(bs, ab + 2048);      gload_lds16(bs + rStep, ab + 2560); \
    gload_lds16(bs + 2*rStep, ab + 3072); gload_lds16(bs + 3*rStep, ab + 3584); }

#define COMPUTE(b) { \
    u16* ab = base + (b) * 4096; \
    short8x a[4], bb[4]; \
    _Pragma("unroll") for (int i = 0; i < 4; ++i) a[i] = *(const short8x*)(ab + aoff[i]); \
    _Pragma("unroll") for (int j = 0; j < 4; ++j) bb[j] = *(const short8x*)(ab + 2048 + boff[j]); \
    _Pragma("unroll") for (int i = 0; i < 4; ++i) \
    _Pragma("unroll") for (int j = 0; j < 4; ++j) \
        acc[i][j] = __builtin_amdgcn_mfma_f32_16x16x32_bf16(a[i], bb[j], acc[i][j], 0, 0, 0); }

    ISSUE(0, 0);
    int c = 0;
    for (; c < nCh - 1; ++c) {
        __builtin_amdgcn_sched_barrier(0);
        ISSUE(c + 1, (c + 1) & 1);
        __builtin_amdgcn_sched_barrier(0);
        __builtin_amdgcn_s_waitcnt(0x0F78);   // vmcnt(8): chunk c staged
        __builtin_amdgcn_sched_barrier(0);
        COMPUTE(c & 1);
    }
    __builtin_amdgcn_sched_barrier(0);
    __builtin_amdgcn_s_waitcnt(0x0F70);       // vmcnt(0): last chunk staged
    __builtin_amdgcn_sched_barrier(0);
    COMPUTE(c & 1);
#undef ISSUE
#undef COMPUTE

    // ---- in-LDS tree reduction of 8 wave-partials (reuse staging space) ----
    // tile p = fp32 64x64 at stage + p*8192 u16 (16KB); frag (i,j) reg r maps to
    // row = i*16 + lq*4 + r, col = j*16 + lm  [C/D layout, m89-verified]
    float* T = (float*)stage;
    __syncthreads();                 // all waves done with staging reads
    if (w < 4) {
        float* tw = T + w * 4096;
#pragma unroll
        for (int i = 0; i < 4; ++i)
#pragma unroll
            for (int j = 0; j < 4; ++j)
#pragma unroll
                for (int r = 0; r < 4; ++r)
                    tw[(i * 16 + lq * 4 + r) * 64 + j * 16 + lm] = acc[i][j][r];
    }
    __syncthreads();
    if (w >= 4) {
        float* tw = T + (w - 4) * 4096;
#pragma unroll
        for (int i = 0; i < 4; ++i)
#pragma unroll
            for (int j = 0; j < 4; ++j)
#pragma unroll
                for (int r = 0; r < 4; ++r)
                    tw[(i * 16 + lq * 4 + r) * 64 + j * 16 + lm] += acc[i][j][r];
    }
    __syncthreads();
    if (w < 2) {        // tile w += tile w+2
        float* d = T + w * 4096;
        const float* s = T + (w + 2) * 4096;
#pragma unroll
        for (int q = 0; q < 16; ++q) {
            int o = l * 64 + q * 4;
            *(float4x*)(d + o) += *(const float4x*)(s + o);
        }
    }
    __syncthreads();
    if (w < 2) {        // tile0 += tile1, split between waves 0 and 1
        float* d = T + w * 2048;
        const float* s = T + 4096 + w * 2048;
#pragma unroll
        for (int q = 0; q < 8; ++q) {
            int o = l * 32 + q * 4;
            *(float4x*)(d + o) += *(const float4x*)(s + o);
        }
    }
    __syncthreads();

    // ---- fused epilogue: thread t handles row = t>>3, cols c8..c8+7 ----
    const int row = t >> 3, c8 = (t & 7) * 8;
    const size_t idx = (size_t)(row0 + row) * g.N + col0 + c8;
    float4x cv[2];
    cv[0] = *(const float4x*)(T + row * 64 + c8);
    cv[1] = *(const float4x*)(T + row * 64 + c8 + 4);

    float lr = 0.f;
    if (EPI == 1 || EPI == 2) lr = *g.lr;
    float lsum = 0.f;

    if (EPI == 1) {
        float4x vv[2], mm[2], nv[2]; u16x8 tb;
        vv[0] = *(const float4x*)(g.x0 + idx);       vv[1] = *(const float4x*)(g.x0 + idx + 4);
        mm[0] = *(const float4x*)(g.x1 + col0 + c8); mm[1] = *(const float4x*)(g.x1 + col0 + c8 + 4);
#pragma unroll
        for (int h = 0; h < 2; ++h)
#pragma unroll
            for (int e = 0; e < 4; ++e) {
                float v = vv[h][e], th = tanhf(v), td = 1.f - th * th;
                float d0 = (mm[h][e] - v) - 0.5f * signf_(v) + td * cv[h][e];
                float x = v + lr * d0;
                x = x > 0.f ? x : 0.f;
                nv[h][e] = x;
                tb[h * 4 + e] = f2b(tanhf(x));
                float ne0 = x - mm[h][e];
                lsum += ne0 * ne0;
            }
        *(float4x*)(g.y0 + idx) = nv[0];
        *(float4x*)(g.y0 + idx + 4) = nv[1];
        *(u16x8*)(g.y1b + idx) = tb;
    } else if (EPI == 2) {
        float4x vv[2], ee[2], nv[2]; u16x8 tb;
        vv[0] = *(const float4x*)(g.x0 + idx);     vv[1] = *(const float4x*)(g.x0 + idx + 4);
        ee[0] = *(const float4x*)(g.x1 + idx);     ee[1] = *(const float4x*)(g.x1 + idx + 4);
#pragma unroll
        for (int h = 0; h < 2; ++h)
#pragma unroll
            for (int e = 0; e < 4; ++e) {
                float v = vv[h][e], th = tanhf(v), td = 1.f - th * th;
                float x = v + lr * (-ee[h][e] + td * cv[h][e]);
                x = x > 0.f ? x : 0.f;
                nv[h][e] = x;
                tb[h * 4 + e] = f2b(tanhf(x));
            }
        *(float4x*)(g.y0 + idx) = nv[0];
        *(float4x*)(g.y0 + idx + 4) = nv[1];
        *(u16x8*)(g.y1b + idx) = tb;
    } else if (EPI == 3) {
        float4x vv[2], ne[2]; u16x8 nb;
        vv[0] = *(const float4x*)(g.x0 + idx);     vv[1] = *(const float4x*)(g.x0 + idx + 4);
#pragma unroll
        for (int h = 0; h < 2; ++h)
#pragma unroll
            for (int e = 0; e < 4; ++e) {
                float x = vv[h][e] - cv[h][e];
                ne[h][e] = x;
                nb[h * 4 + e] = f2b(x);
                lsum += x * x;
            }
        *(float4x*)(g.y0 + idx) = ne[0];
        *(float4x*)(g.y0 + idx + 4) = ne[1];
        *(u16x8*)(g.y0b + idx) = nb;
    } else {
        float4x vv[2]; u16x8 nb;
        vv[0] = *(const float4x*)(g.x0 + idx);     vv[1] = *(const float4x*)(g.x0 + idx + 4);
#pragma unroll
        for (int h = 0; h < 2; ++h)
#pragma unroll
            for (int e = 0; e < 4; ++e) {
                float x = vv[h][e] - cv[h][e];
                nb[h * 4 + e] = f2b(x);
                lsum += x * x;
            }
        *(u16x8*)(g.y1b + idx) = nb;
    }

    if (EPI != 2) {
#pragma unroll
        for (int off = 32; off > 0; off >>= 1) lsum += __shfl_down(lsum, off);
        if (l == 0) red8[w] = lsum;
        __syncthreads();
        if (t == 0) {
            float s = 0.f;
#pragma unroll
            for (int q = 0; q < 8; ++q) s += red8[q];
            atomicAdd(g.loss, s * LOSS_SCALE);
        }
    }
}

template <int EPIA, int EPIB>
__global__ __launch_bounds__(512, 2) void pcn_pair(GDR ga, GDR gb, int nA) {
    __shared__ u16 stage[65536];   // 128 KB
    __shared__ float red8[8];
    int bx = blockIdx.x;
    if (bx < nA) gemm_tile<EPIA>(ga, bx, stage, red8);
    else         gemm_tile<EPIB>(gb, bx - nA, stage, red8);
}

extern "C" void kernel_launch(void* const* d_in, const int* in_sizes, int n_in,
                              void* d_out, int out_size, void* d_ws, size_t ws_size,
                              hipStream_t stream)
{
    const float* batch_inp = (const float*)d_in[0]; // (256, 8192)
    const float* W0        = (const float*)d_in[1]; // (4096, 2048)
    const float* W1        = (const float*)d_in[2]; // (8192, 4096)
    const float* memory    = (const float*)d_in[3]; // (2048,)
    const float* lr_ptr    = (const float*)d_in[5]; // 0.05
    float* out = (float*)d_out;                     // 8 losses

    const int n0 = 2048, n1 = 4096, n2 = 8192, Bn = 256;

    // ---- workspace layout ----
    char* ws = (char*)d_ws;
    auto alloc_f = [&](size_t n) { float* p = (float*)ws; ws += n * 4; return p; };
    auto alloc_b = [&](size_t n) { u16* p = (u16*)ws; ws += n * 2; return p; };

    float* v0  = alloc_f((size_t)Bn * n0);
    float* v1  = alloc_f((size_t)Bn * n1);
    float* e1  = alloc_f((size_t)Bn * n1);
    u16*   e1b = alloc_b((size_t)Bn * n1);
    u16*   e2b = alloc_b((size_t)Bn * n2);
    u16*   T0b = alloc_b((size_t)Bn * n0);
    u16*   T1b = alloc_b((size_t)Bn * n1);
    u16*   W0b  = alloc_b((size_t)n1 * n0);   // (n1, n0) = W0 cast
    u16*   W0Tb = alloc_b((size_t)n0 * n1);   // (n0, n1) = W0^T cast
    u16*   W1b  = alloc_b((size_t)n2 * n1);   // (n2, n1) = W1 cast
    u16*   W1Tb = alloc_b((size_t)n1 * n2);   // (n1, n2) = W1^T cast
    float* tm = alloc_f(n0);
    float* r1 = alloc_f(n1);
    float* t1 = alloc_f(n1);
    float* r2 = alloc_f(n2);

    // ---- one-time init ----
    k_zero<<<1, 32, 0, stream>>>(out, 8);
    k_cast_both<<<dim3(n0 / 32, n1 / 32), dim3(32, 8), 0, stream>>>(W0, W0b, W0Tb, n1, n0);
    k_cast_both<<<dim3(n1 / 32, n2 / 32), dim3(32, 8), 0, stream>>>(W1, W1b, W1Tb, n2, n1);
    k_fill_v0<<<(Bn * n0) / 256, 256, 0, stream>>>(v0, memory, Bn * n0, n0 - 1);
    k_tanh<<<n0 / 256, 256, 0, stream>>>(tm, memory, n0);
    k_rowdot<<<n1, 256, 0, stream>>>(tm, W0, r1, n0);        // r1 = tanh(mem) @ W0^T
    k_tanh<<<n1 / 256, 256, 0, stream>>>(t1, r1, n1);
    k_bcast_v1_e1<<<(Bn * n1) / 256, 256, 0, stream>>>(v1, e1, e1b, r1, Bn * n1, n1 - 1);
    k_rowdot<<<n2, 256, 0, stream>>>(t1, W1, r2, n1);        // r2 = tanh(r1) @ W1^T
    k_e2_init<<<(Bn * n2) / 256, 256, 0, stream>>>(e2b, batch_inp, r2, Bn * n2, n2 - 1);

    // ---- 8 inference iterations ----
    for (int it = 0; it < 8; ++it) {
        float* loss = out + it;

        // phase 1: G2 (256 tiles) || G1 (128 tiles) — 384 blocks x 512 thr
        GDR g2{e2b, W1Tb, v1, e1, v1, nullptr, T1b, nullptr, lr_ptr, n1, n2, n1 / 64};
        GDR g1{e1b, W0Tb, v0, memory, v0, nullptr, T0b, loss, lr_ptr, n0, n1, n0 / 64};
        pcn_pair<2, 1><<<4 * (n1 / 64) + 4 * (n0 / 64), 512, 0, stream>>>(
            g2, g1, 4 * (n1 / 64));

        // phase 2: G4 (512 tiles) || G3 (256 tiles) — 768 blocks x 512 thr
        GDR g4{T1b, W1b, batch_inp, nullptr, nullptr, nullptr, e2b, loss, nullptr, n2, n1, n2 / 64};
        GDR g3{T0b, W0b, v1, nullptr, e1, e1b, nullptr, loss, nullptr, n1, n0, n1 / 64};
        pcn_pair<4, 3><<<4 * (n2 / 64) + 4 * (n1 / 64), 512, 0, stream>>>(
            g4, g3, 4 * (n2 / 64));
    }
}